// Round 1
// 419.495 us; speedup vs baseline: 1.0225x; 1.0225x over previous
//
#include <hip/hip_runtime.h>
#include <hip/hip_fp16.h>

static constexpr float FILLW = 2.0f;
static constexpr int PADB = 16;   // ints per histogram bin -> one 64B line per bin
static constexpr int HEPT = 16;   // edges per thread, histogram (atomic ILP)
static constexpr int FEPT = 8;    // edges per thread, fill (gather/scatter ILP)

// ============================ scan (3-phase) ============================

// Phase A: scan 1024 bins/block from padded histogram -> compact excl offsets.
__global__ void k_scanA(const int* __restrict__ cntPad, int* __restrict__ woff,
                        int* __restrict__ bsum, int N, int SB){
    int t = blockIdx.x / SB, bb = blockIdx.x % SB;
    int base = bb * 1024 + threadIdx.x * 4;
    const int* cp = cntPad + (size_t)t * N * PADB;
    int4 v = {0,0,0,0};
    if (base     < N) v.x = cp[(size_t)(base    ) * PADB];
    if (base + 1 < N) v.y = cp[(size_t)(base + 1) * PADB];
    if (base + 2 < N) v.z = cp[(size_t)(base + 2) * PADB];
    if (base + 3 < N) v.w = cp[(size_t)(base + 3) * PADB];
    int s = v.x + v.y + v.z + v.w;
    int lane = threadIdx.x & 63, wv = threadIdx.x >> 6;
    int sc = s;
    #pragma unroll
    for (int o = 1; o < 64; o <<= 1){ int u = __shfl_up(sc, o); if (lane >= o) sc += u; }
    __shared__ int ws[4];
    if (lane == 63) ws[wv] = sc;
    __syncthreads();
    int wbase = 0;
    #pragma unroll
    for (int k = 0; k < 4; ++k) if (k < wv) wbase += ws[k];
    int excl = wbase + sc - s;
    int4 o;
    o.x = excl; o.y = o.x + v.x; o.z = o.y + v.y; o.w = o.z + v.z;
    int* wo = woff + t * N;
    if (base     < N) wo[base]     = o.x;
    if (base + 1 < N) wo[base + 1] = o.y;
    if (base + 2 < N) wo[base + 2] = o.z;
    if (base + 3 < N) wo[base + 3] = o.w;
    if (threadIdx.x == 255) bsum[blockIdx.x] = o.w + v.w;
}

__global__ void k_scanB(int* __restrict__ bsum, int total, int SB){
    __shared__ int s[256];
    int i = threadIdx.x;
    s[i] = (i < total) ? bsum[i] : 0;
    __syncthreads();
    if (i == 0){
        int acc = 0;
        for (int k = 0; k < total; ++k){
            if (k % SB == 0) acc = 0;
            int tv = s[k]; s[k] = acc; acc += tv;
        }
    }
    __syncthreads();
    if (i < total) bsum[i] = s[i];
}

__global__ void k_scanC(int* __restrict__ woff, const int* __restrict__ bsum,
                        int N, int SB, int GN){
    int i = blockIdx.x * 256 + threadIdx.x;
    if (i < GN){
        int t = i >= N, off = i - t * N;
        woff[i] += bsum[t * SB + off / 1024];
    }
}

// ======================= register-blocked GEMM tile =======================
template<int F, int K, int TR, int KC, bool SCALE, typename OutT>
__device__ __forceinline__ void gemm_tile(const float* __restrict__ A,
        const float* __restrict__ W, OutT* __restrict__ C,
        const float* __restrict__ dv, int rb, int N,
        float* __restrict__ Ws, float* __restrict__ As){
    constexpr int NCH = K / KC;
    constexpr int TRp = TR + 4;
    constexpr int CG  = F / 8;
    constexpr int LPT = TR * KC / 1024;
    const int tid = threadIdx.x;
    for (int i = tid; i < K * F / 4; i += 256)
        ((float4*)Ws)[i] = ((const float4*)W)[i];
    const int tx = tid % CG, ty = tid / CG;
    const int c0 = tx * 8, r0 = ty * 8;

    float acc[8][8];
    #pragma unroll
    for (int i = 0; i < 8; ++i)
        #pragma unroll
        for (int j = 0; j < 8; ++j) acc[i][j] = 0.f;

    float4 st[LPT];
    auto gload = [&](int kc){
        #pragma unroll
        for (int l2 = 0; l2 < LPT; ++l2){
            int l = l2 * 256 + tid;
            int r = l / (KC / 4);
            int kk = (l % (KC / 4)) * 4;
            int ar = rb + r; if (ar >= N) ar = N - 1;
            st[l2] = *(const float4*)(A + (size_t)ar * K + kc * KC + kk);
        }
    };
    auto swrite = [&](int buf){
        float* p = As + buf * (KC * TRp);
        #pragma unroll
        for (int l2 = 0; l2 < LPT; ++l2){
            int l = l2 * 256 + tid;
            int r = l / (KC / 4);
            int kk = (l % (KC / 4)) * 4;
            p[(kk+0)*TRp + r] = st[l2].x;
            p[(kk+1)*TRp + r] = st[l2].y;
            p[(kk+2)*TRp + r] = st[l2].z;
            p[(kk+3)*TRp + r] = st[l2].w;
        }
    };

    gload(0); swrite(0);
    __syncthreads();
    for (int kc = 0; kc < NCH; ++kc){
        if (kc + 1 < NCH) gload(kc + 1);
        const float* Ab = As + (kc & 1) * (KC * TRp);
        #pragma unroll
        for (int j = 0; j < KC; ++j){
            const float* wrow = Ws + (kc * KC + j) * F + c0;
            float4 w0 = *(const float4*)(wrow);
            float4 w1 = *(const float4*)(wrow + 4);
            float4 a0 = *(const float4*)(Ab + j * TRp + r0);
            float4 a1 = *(const float4*)(Ab + j * TRp + r0 + 4);
            float av[8] = {a0.x,a0.y,a0.z,a0.w,a1.x,a1.y,a1.z,a1.w};
            float wvv[8] = {w0.x,w0.y,w0.z,w0.w,w1.x,w1.y,w1.z,w1.w};
            #pragma unroll
            for (int rr = 0; rr < 8; ++rr)
                #pragma unroll
                for (int cc = 0; cc < 8; ++cc)
                    acc[rr][cc] = fmaf(av[rr], wvv[cc], acc[rr][cc]);
        }
        if (kc + 1 < NCH){ swrite((kc + 1) & 1); __syncthreads(); }
    }
    #pragma unroll
    for (int rr = 0; rr < 8; ++rr){
        int row = rb + r0 + rr;
        if (row < N){
            float scv = 1.0f;
            if constexpr (SCALE) scv = dv[row];
            if constexpr (sizeof(OutT) == 2){
                __half2 o2[4];
                #pragma unroll
                for (int q = 0; q < 4; ++q)
                    o2[q] = __floats2half2_rn(acc[rr][2*q]*scv, acc[rr][2*q+1]*scv);
                *(float4*)((__half*)C + (size_t)row * F + c0) = *(float4*)o2;
            } else {
                float4 o0 = {acc[rr][0]*scv, acc[rr][1]*scv, acc[rr][2]*scv, acc[rr][3]*scv};
                float4 o1 = {acc[rr][4]*scv, acc[rr][5]*scv, acc[rr][6]*scv, acc[rr][7]*scv};
                *(float4*)((float*)C + (size_t)row * F + c0)     = o0;
                *(float4*)((float*)C + (size_t)row * F + c0 + 4) = o1;
            }
        }
    }
}

// ===== fused: GEMM1 (fp16 out) + dst histogram (padded bins) w/ rank =====
// Histogram side: HEPT edges/thread, phase-split (loads -> atomics -> stores)
// so the 16 returning atomics pipeline in the VMEM queue instead of exposing
// one full round-trip latency per thread.
__global__ void __launch_bounds__(256) k_cg1(const float* __restrict__ x0,
        const float* __restrict__ x1, const float* __restrict__ W1,
        __half* __restrict__ h0, __half* __restrict__ h1,
        const int* __restrict__ dst0, const int* __restrict__ dst1,
        int* __restrict__ cntPad, int* __restrict__ rank,
        int N, int E, int BPT, int GB, int HB){
    if ((int)blockIdx.x < GB){
        __shared__ float Ws[64 * 128];
        __shared__ float As[2 * 8 * 260];
        int t  = (int)blockIdx.x >= BPT;
        int rb = ((int)blockIdx.x - t * BPT) * 256;
        gemm_tile<64,128,256,8,false,__half>(t ? x1 : x0, W1, t ? h1 : h0,
                                             nullptr, rb, N, Ws, As);
        return;
    }
    int c = (int)blockIdx.x - GB;
    int t = c >= HB;
    int base = (c - t * HB) * (256 * HEPT) + (int)threadIdx.x;
    const int* dp = t ? dst1 : dst0;
    int* rk = rank + (size_t)t * E;
    int* cp = cntPad + (size_t)t * N * PADB;

    int d[HEPT];
    #pragma unroll
    for (int q = 0; q < HEPT; ++q){
        int e = base + q * 256;
        d[q] = (e < E) ? dp[e] : -1;
    }
    int r[HEPT];
    #pragma unroll
    for (int q = 0; q < HEPT; ++q)
        if (d[q] >= 0) r[q] = atomicAdd(&cp[(size_t)d[q] * PADB], 1);
    #pragma unroll
    for (int q = 0; q < HEPT; ++q){
        int e = base + q * 256;
        if (d[q] >= 0) rk[e] = r[q];
    }
}

// =============== fill (no atomics: offset[d] + saved rank) ===============
// FEPT edges/thread, phase-split so the random woff[d] gathers and the
// scattered sn stores overlap across edges.
__global__ void __launch_bounds__(256) k_fill(const int* __restrict__ src0,
                       const int* __restrict__ src1,
                       const int* __restrict__ dst0, const int* __restrict__ dst1,
                       const float* __restrict__ ew0, const float* __restrict__ ew1,
                       const int* __restrict__ woff, const int* __restrict__ rank,
                       float2* __restrict__ sn, int N, int E, int FB){
    int t = (int)blockIdx.x >= FB;
    int base = ((int)blockIdx.x - t * FB) * (256 * FEPT) + (int)threadIdx.x;
    const int* sp = t ? src1 : src0;
    const int* dp = t ? dst1 : dst0;
    const float* wp = t ? ew1 : ew0;
    const int* rk = rank + (size_t)t * E;
    const int* wo = woff + t * N;
    float2* so = sn + (size_t)t * E;

    int s[FEPT], d[FEPT], r[FEPT]; float w[FEPT];
    #pragma unroll
    for (int q = 0; q < FEPT; ++q){
        int e = base + q * 256;
        if (e < E){
            s[q] = sp[e];
            d[q] = dp[e];
            w[q] = fmaxf(wp[e], 0.f);
            r[q] = rk[e];
        } else d[q] = -1;
    }
    int o[FEPT];
    #pragma unroll
    for (int q = 0; q < FEPT; ++q)
        if (d[q] >= 0) o[q] = wo[d[q]];
    #pragma unroll
    for (int q = 0; q < FEPT; ++q)
        if (d[q] >= 0) so[o[q] + r[q]] = make_float2(__int_as_float(s[q]), w[q]);
}

// ==== dinv = rsqrt(FILLW + CSR segment-sum); prescale h1 rows (fp16) ====
__global__ void __launch_bounds__(256) k_degdinv(const int* __restrict__ woff,
        const float2* __restrict__ sn, float* __restrict__ dinv,
        __half* __restrict__ h1buf, int N, int E, int GN){
    int g = (int)blockIdx.x * 256 + threadIdx.x;
    float dv = 0.f;
    if (g < GN){
        int t = g >= N;
        int n = g - t * N;
        int beg = woff[g];
        int end = (n == N - 1) ? E : woff[g + 1];
        const float2* s = sn + (size_t)t * E;
        float a0 = 0.f, a1 = 0.f, a2 = 0.f, a3 = 0.f;
        int j = beg;
        for (; j + 4 <= end; j += 4){
            float2 v0 = s[j], v1 = s[j+1], v2 = s[j+2], v3 = s[j+3];
            a0 += v0.y; a1 += v1.y; a2 += v2.y; a3 += v3.y;
        }
        float acc = FILLW + (a0 + a1) + (a2 + a3);
        for (; j < end; ++j) acc += s[j].y;
        dv = rsqrtf(acc);
        dinv[g] = dv;
    }
    int lane  = threadIdx.x & 63;
    int wbase = (int)blockIdx.x * 256 + (threadIdx.x & ~63);
    for (int r = 0; r < 64; ++r){
        int gr = wbase + r;
        float scv = __shfl(dv, r);
        if (gr < GN){
            __half* row = h1buf + (size_t)gr * 64;
            row[lane] = __float2half(__half2float(row[lane]) * scv);
        }
    }
}

// ================== GEMM2: fp32 in, dinv-prescaled fp16 out ==================
__global__ void __launch_bounds__(256) k_gemm2(const float* __restrict__ A0,
        const float* __restrict__ A1, const float* __restrict__ W,
        __half* __restrict__ C0, __half* __restrict__ C1,
        const float* __restrict__ dinv, int N, int BPT){
    __shared__ float Ws[64 * 128];
    __shared__ float As[2 * 16 * 132];
    int t  = (int)blockIdx.x >= BPT;
    int rb = ((int)blockIdx.x - t * BPT) * 128;
    gemm_tile<128,64,128,16,true,__half>(t ? A1 : A0, W, t ? C1 : C0,
                                         dinv + t * N, rb, N, BPT ? Ws : Ws, As);
}

// ===== CSR gather-max: coalesced edge-record load + shfl broadcast + deep unroll =====
template<int F, int V, int UNR>   // V = F/64 values per lane
__global__ void __launch_bounds__(256) k_agg(const int* __restrict__ woff,
        const float2* __restrict__ sn, const float* __restrict__ dinv,
        const __half* __restrict__ H0, const __half* __restrict__ H1,
        const float* __restrict__ bias, float* __restrict__ O0, float* __restrict__ O1,
        int N, int E, int BPT){
    const int t = (int)blockIdx.x >= BPT;
    const int lane = threadIdx.x & 63, wv = threadIdx.x >> 6;
    int n = ((int)blockIdx.x - t * BPT) * 4 + wv;
    if (n >= N) return;
    int g = t * N + n;
    int beg = woff[g];
    int end = (n == N - 1) ? E : woff[g + 1];
    int cnt = end - beg;
    const float2* st = sn + (size_t)t * E;
    const __half* H = t ? H1 : H0;
    float* O = t ? O1 : O0;
    float di = dinv[g];
    float v0, v1 = 0.f;
    if (V == 1) {
        v0 = FILLW * __half2float(H[(size_t)n * F + lane]);
    } else {
        float2 h = __half22float2(((const __half2*)H)[(size_t)n * (F/2) + lane]);
        v0 = FILLW * h.x; v1 = FILLW * h.y;
    }
    for (int base = 0; base < cnt; base += 64){
        int m = cnt - base; if (m > 64) m = 64;
        float2 er = make_float2(0.f, 0.f);
        if (lane < m) er = st[beg + base + lane];     // ONE coalesced load: 64 records
        int   es = __float_as_int(er.x);
        float ew = er.y;
        int j = 0;
        for (; j + UNR <= m; j += UNR){
            int ss[UNR]; float ww[UNR];
            #pragma unroll
            for (int q = 0; q < UNR; ++q){ ss[q] = __shfl(es, j + q); ww[q] = __shfl(ew, j + q); }
            if (V == 1){
                float hh[UNR];
                #pragma unroll
                for (int q = 0; q < UNR; ++q)
                    hh[q] = __half2float(H[(size_t)ss[q] * F + lane]);   // UNR independent gathers
                #pragma unroll
                for (int q = 0; q < UNR; ++q) v0 = fmaxf(v0, ww[q] * hh[q]);
            } else {
                float2 hh[UNR];
                #pragma unroll
                for (int q = 0; q < UNR; ++q)
                    hh[q] = __half22float2(((const __half2*)H)[(size_t)ss[q] * (F/2) + lane]);
                #pragma unroll
                for (int q = 0; q < UNR; ++q){
                    v0 = fmaxf(v0, ww[q] * hh[q].x);
                    v1 = fmaxf(v1, ww[q] * hh[q].y);
                }
            }
        }
        for (; j < m; ++j){
            int s = __shfl(es, j); float w = __shfl(ew, j);
            if (V == 1){
                v0 = fmaxf(v0, w * __half2float(H[(size_t)s * F + lane]));
            } else {
                float2 h = __half22float2(((const __half2*)H)[(size_t)s * (F/2) + lane]);
                v0 = fmaxf(v0, w * h.x); v1 = fmaxf(v1, w * h.y);
            }
        }
    }
    if (V == 1) {
        O[(size_t)n * F + lane] = di * v0 + bias[lane];
    } else {
        float2 bb = ((const float2*)bias)[lane];
        ((float2*)O)[(size_t)n * (F/2) + lane] = make_float2(di*v0 + bb.x, di*v1 + bb.y);
    }
}

// ============================== host ==============================

extern "C" void kernel_launch(void* const* d_in, const int* in_sizes, int n_in,
                              void* d_out, int out_size, void* d_ws, size_t ws_size,
                              hipStream_t stream){
    const int E  = in_sizes[2];        // 800000
    const int F1 = in_sizes[7];        // 64
    const int F2 = in_sizes[9];        // 128
    const int IN = in_sizes[6] / F1;   // 128
    const int N  = in_sizes[0] / IN;   // 50000
    const int SB = (N + 1023) / 1024;

    const float* W1 = (const float*)d_in[6];
    const float* b1 = (const float*)d_in[7];
    const float* W2 = (const float*)d_in[8];
    const float* b2 = (const float*)d_in[9];

    auto need = [&](int G){
        return (size_t)G * E * 8              // sn
             + (size_t)G * N * F2 * 2         // hbuf (fp16)
             + (size_t)G * N * F1 * 4         // out1 (rank overlays)
             + (size_t)G * N * 8              // dinv + woff
             + (size_t)G * N * PADB * 4       // padded histogram
             + 8192;                          // bsum + slack
    };
    const int G = (ws_size >= need(2)) ? 2 : 1;

    float2* sn     = (float2*)d_ws;                        // G*E float2
    __half* hbuf   = (__half*)(sn + (size_t)G * E);        // G*N*F2 halves
    float*  out1   = (float*)(hbuf + (size_t)G * N * F2);  // G*N*F1 floats
    int*    rank   = (int*)out1;                           // G*E ints (dead before agg1)
    float*  dinv   = out1 + (size_t)G * N * F1;            // G*N
    int*    woff   = (int*)(dinv + G * N);                 // G*N
    int*    bsum   = woff + G * N;                         // <=256
    int*    cntPad = bsum + 512;                           // G*N*PADB

    const int GN   = G * N;
    const int HB   = (E + 256 * HEPT - 1) / (256 * HEPT);  // histogram blocks/tower
    const int FB   = (E + 256 * FEPT - 1) / (256 * FEPT);  // fill blocks/tower
    const int BPT1 = (N + 255) / 256;
    const int BPT2 = (N + 127) / 128;
    const int ABT  = (N + 3) / 4;
    const int GB   = G * BPT1;

    for (int it = 0; it < 2; it += G){
        int t0 = it, t1 = (G == 2) ? it + 1 : it;
        const float* x0 = (const float*)d_in[t0*3], * x1 = (const float*)d_in[t1*3];
        const int* ei0 = (const int*)d_in[t0*3+1], * ei1 = (const int*)d_in[t1*3+1];
        const float* ew0 = (const float*)d_in[t0*3+2], * ew1 = (const float*)d_in[t1*3+2];
        const int* src0 = ei0, * dst0 = ei0 + E;
        const int* src1 = ei1, * dst1 = ei1 + E;
        __half* h1_0 = hbuf,  * h1_1 = hbuf + (size_t)(G-1) * N * F1;
        __half* h2_0 = hbuf,  * h2_1 = hbuf + (size_t)(G-1) * N * F2;
        float* o1_0 = out1, * o1_1 = out1 + (size_t)(G-1) * N * F1;
        float* go0 = (float*)d_out + (size_t)t0 * N * F2;
        float* go1 = (float*)d_out + (size_t)t1 * N * F2;

        hipMemsetAsync(cntPad, 0, (size_t)GN * PADB * sizeof(int), stream);
        k_cg1<<<GB + G * HB, 256, 0, stream>>>(x0, x1, W1, h1_0, h1_1,
                                               dst0, dst1, cntPad, rank, N, E, BPT1, GB, HB);
        k_scanA<<<G * SB, 256, 0, stream>>>(cntPad, woff, bsum, N, SB);
        k_scanB<<<1, 256, 0, stream>>>(bsum, G * SB, SB);
        k_scanC<<<(GN + 255) / 256, 256, 0, stream>>>(woff, bsum, N, SB, GN);
        k_fill<<<G * FB, 256, 0, stream>>>(src0, src1, dst0, dst1, ew0, ew1,
                                           woff, rank, sn, N, E, FB);
        k_degdinv<<<(GN + 255) / 256, 256, 0, stream>>>(woff, sn, dinv, hbuf, N, E, GN);
        k_agg<64,1,8><<<G * ABT, 256, 0, stream>>>(woff, sn, dinv, h1_0, h1_1, b1,
                                                   o1_0, o1_1, N, E, ABT);
        k_gemm2<<<G * BPT2, 256, 0, stream>>>(o1_0, o1_1, W2, h2_0, h2_1, dinv, N, BPT2);
        k_agg<128,2,8><<<G * ABT, 256, 0, stream>>>(woff, sn, dinv, h2_0, h2_1, b2,
                                                    go0, go1, N, E, ABT);
    }
}